// Round 11
// baseline (22769.693 us; speedup 1.0000x reference)
//
#include <hip/hip_runtime.h>
#include <math.h>

#define B_ 32
#define N_ 1024
#define C_ 512
#define H_ 256
#define V_ 50
#define T_ 501
#define CV_ 562      // C + V
#define G3_ 768      // 3*H
#define ATTN_BLKS 512
#define GATE_BLKS 48
#define TAIL_BLKS 32
#define WORK_BLKS 80
#define CHUNKS_ 16   // attn blocks per batch row
// 64 positions per attn block (4 waves x 16)

typedef float    f32x4 __attribute__((ext_vector_type(4)));
typedef _Float16 f16x4 __attribute__((ext_vector_type(4)));
typedef _Float16 f16x8 __attribute__((ext_vector_type(8)));

__device__ __forceinline__ float fast_rcp(float x) { return __builtin_amdgcn_rcpf(x); }
__device__ __forceinline__ float fast_tanh(float x) {
  float e = __expf(2.0f * x);
  return 1.0f - 2.0f * fast_rcp(e + 1.0f);
}
__device__ __forceinline__ float fast_sigmoid(float x) {
  return fast_rcp(1.0f + __expf(-x));
}
__device__ __forceinline__ float aload(const float* p) {
  return __hip_atomic_load(p, __ATOMIC_RELAXED, __HIP_MEMORY_SCOPE_AGENT);
}
__device__ __forceinline__ int aloadi(const int* p) {
  return __hip_atomic_load(p, __ATOMIC_RELAXED, __HIP_MEMORY_SCOPE_AGENT);
}

// ---------------- feat_proj GEMM: FPh[m][h] = fp16( sum_c A[m][c] * W[h][c] ) ----------------
__global__ __launch_bounds__(256) void fp_gemm(const float* __restrict__ A,
                                               const float* __restrict__ W,
                                               _Float16* __restrict__ FPh) {
  __shared__ __align__(16) float As[16][68];
  __shared__ __align__(16) float Ws[16][68];
  const int t = threadIdx.x;
  const int m0 = blockIdx.x * 64;
  const int h0 = blockIdx.y * 64;
  const int lr = t & 63;
  const int kg = t >> 6;
  const int tx = t & 15, ty = t >> 4;
  float acc[4][4] = {};
  for (int k0 = 0; k0 < C_; k0 += 16) {
    float4 av = *(const float4*)&A[(size_t)(m0 + lr) * C_ + k0 + kg * 4];
    float4 wv = *(const float4*)&W[(size_t)(h0 + lr) * C_ + k0 + kg * 4];
    As[kg*4+0][lr] = av.x; As[kg*4+1][lr] = av.y; As[kg*4+2][lr] = av.z; As[kg*4+3][lr] = av.w;
    Ws[kg*4+0][lr] = wv.x; Ws[kg*4+1][lr] = wv.y; Ws[kg*4+2][lr] = wv.z; Ws[kg*4+3][lr] = wv.w;
    __syncthreads();
#pragma unroll
    for (int kk = 0; kk < 16; ++kk) {
      float4 a = *(const float4*)&As[kk][ty * 4];
      float4 w = *(const float4*)&Ws[kk][tx * 4];
      acc[0][0] += a.x*w.x; acc[0][1] += a.x*w.y; acc[0][2] += a.x*w.z; acc[0][3] += a.x*w.w;
      acc[1][0] += a.y*w.x; acc[1][1] += a.y*w.y; acc[1][2] += a.y*w.z; acc[1][3] += a.y*w.w;
      acc[2][0] += a.z*w.x; acc[2][1] += a.z*w.y; acc[2][2] += a.z*w.z; acc[2][3] += a.z*w.w;
      acc[3][0] += a.w*w.x; acc[3][1] += a.w*w.y; acc[3][2] += a.w*w.z; acc[3][3] += a.w*w.w;
    }
    __syncthreads();
  }
#pragma unroll
  for (int i = 0; i < 4; ++i) {
    f16x4 o;
    o.x = (_Float16)acc[i][0]; o.y = (_Float16)acc[i][1];
    o.z = (_Float16)acc[i][2]; o.w = (_Float16)acc[i][3];
    *(f16x4*)&FPh[(size_t)(m0 + ty*4 + i) * H_ + h0 + tx*4] = o;
  }
}

// ---------------- feat -> fp16 (one-time) ----------------
__global__ void feat_to_fp16(const float* __restrict__ src, _Float16* __restrict__ dst,
                             int total4) {
  int i = blockIdx.x * 256 + threadIdx.x;
  if (i >= total4) return;
  f32x4 v = *(const f32x4*)&src[(size_t)i * 4];
  f16x4 o; o.x = (_Float16)v.x; o.y = (_Float16)v.y; o.z = (_Float16)v.z; o.w = (_Float16)v.w;
  *(f16x4*)&dst[(size_t)i * 4] = o;
}

// ---------------- weight transpose (one-time) ----------------
__global__ void transpose_split(const float* __restrict__ src, float* __restrict__ dstA,
                                float* __restrict__ dstB, int rows, int cols, int splitc) {
  int i = blockIdx.x * 256 + threadIdx.x;
  if (i >= rows * cols) return;
  int j = i / cols, c = i - j * cols;
  float v = src[i];
  if (c < splitc) dstA[(size_t)c * rows + j] = v;
  else            dstB[(size_t)(c - splitc) * rows + j] = v;
}

// ---------------- init ----------------
__global__ void init_kernel(const float* __restrict__ b_h2h, float* __restrict__ h,
                            float* __restrict__ pp, int* __restrict__ pre,
                            float* __restrict__ ctx_raw, float* __restrict__ l_total,
                            float* __restrict__ gi_raw, float* __restrict__ gh_raw,
                            int* __restrict__ cnt) {
  int i = blockIdx.x * blockDim.x + threadIdx.x;   // grid 128*256 = 32768
  if (i < B_ * H_) { h[i] = 0.0f; pp[i] = b_h2h[i & (H_ - 1)]; }
  if (i < B_ * C_) ctx_raw[i] = 0.0f;
  if (i < B_ * G3_) { gi_raw[i] = 0.0f; gh_raw[i] = 0.0f; }
  if (i < T_ * 2) cnt[i] = 0;
  if (i < B_) { pre[i] = 0; l_total[i] = 0.0f; }
}

// ================= fused per-step kernel: attn -> gates -> tail =================
// grid = 512 blocks x 256 threads. Roles by arrival ticket; no fences, atomics only.
__global__ __launch_bounds__(256) void step_fused(
    int tstep,
    const _Float16* __restrict__ feath, const _Float16* __restrict__ fph,
    const float* __restrict__ w_score, float* __restrict__ pp,
    float* __restrict__ ctx_raw, float* __restrict__ l_total,
    float* __restrict__ gi_raw, float* __restrict__ gh_raw,
    const float* __restrict__ WtA, const float* __restrict__ WtH,
    const float* __restrict__ WtO,
    const float* __restrict__ b_gru_ih, const float* __restrict__ b_gru_hh,
    const float* __restrict__ Wt_s1, const float* __restrict__ b_s1,
    const float* __restrict__ Wt_h2h, const float* __restrict__ b_h2h,
    const float* __restrict__ w_s2, const float* __restrict__ b_s2,
    float* __restrict__ h, int* __restrict__ pre,
    int* __restrict__ cnt, float* __restrict__ out) {
  __shared__ __align__(16) float smem[6144];   // 24 KB, re-used per phase
  __shared__ float lds_l[4];
  __shared__ int sticket;

  const int t = threadIdx.x;
  const int wv = t >> 6;
  const int lane = t & 63;
  int* c1 = &cnt[tstep * 2];
  int* c2 = &cnt[tstep * 2 + 1];

  // ---------------- phase 1: attention (all blocks) ----------------
  {
    const int b = blockIdx.x >> 4;
    const int chunk = blockIdx.x & (CHUNKS_ - 1);
    float4 ppr = *(const float4*)&pp[b * H_ + lane * 4];
    float4 wsr = *(const float4*)&w_score[lane * 4];
    float aA0 = 0.f, aA1 = 0.f, aA2 = 0.f, aA3 = 0.f;
    float aB0 = 0.f, aB1 = 0.f, aB2 = 0.f, aB3 = 0.f;
    float lacc = 0.f;
    const _Float16* fphb = fph + (size_t)b * N_ * H_;
    const _Float16* fbb  = feath + (size_t)b * N_ * C_;
    const int n0 = chunk * 64 + wv * 16;
#pragma unroll 2
    for (int i = 0; i < 16; ++i) {
      const int n = n0 + i;
      f16x4 v = __builtin_nontemporal_load((const f16x4*)&fphb[(size_t)n * H_ + lane * 4]);
      float s = fast_tanh((float)v.x + ppr.x) * wsr.x + fast_tanh((float)v.y + ppr.y) * wsr.y
              + fast_tanh((float)v.z + ppr.z) * wsr.z + fast_tanh((float)v.w + ppr.w) * wsr.w;
#pragma unroll
      for (int off = 32; off > 0; off >>= 1) s += __shfl_xor(s, off);
      float p = __expf(s);   // |s| <= sum|w_score| ~ 10: safe without max-subtraction
      lacc += p;
      f16x8 f = __builtin_nontemporal_load((const f16x8*)&fbb[(size_t)n * C_ + lane * 8]);
      aA0 += p * (float)f.s0; aA1 += p * (float)f.s1; aA2 += p * (float)f.s2; aA3 += p * (float)f.s3;
      aB0 += p * (float)f.s4; aB1 += p * (float)f.s5; aB2 += p * (float)f.s6; aB3 += p * (float)f.s7;
    }
    {
      float4 o0; o0.x = aA0; o0.y = aA1; o0.z = aA2; o0.w = aA3;
      float4 o1; o1.x = aB0; o1.y = aB1; o1.z = aB2; o1.w = aB3;
      *(float4*)&smem[wv * C_ + lane * 8] = o0;
      *(float4*)&smem[wv * C_ + lane * 8 + 4] = o1;
    }
    if (lane == 0) lds_l[wv] = lacc;
    __syncthreads();
    {
      float c0v = smem[t] + smem[C_ + t] + smem[2 * C_ + t] + smem[3 * C_ + t];
      float c1v = smem[t + 256] + smem[C_ + t + 256] + smem[2 * C_ + t + 256] + smem[3 * C_ + t + 256];
      unsafeAtomicAdd(&ctx_raw[b * C_ + t], c0v);
      unsafeAtomicAdd(&ctx_raw[b * C_ + t + 256], c1v);
      if (t == 0) unsafeAtomicAdd(&l_total[b], lds_l[0] + lds_l[1] + lds_l[2] + lds_l[3]);
    }
  }
  // release: make sure THIS wave's atomics are performed before the ticket
  asm volatile("s_waitcnt vmcnt(0)" ::: "memory");
  __syncthreads();
  if (t == 0) sticket = atomicAdd(c1, 1);
  __syncthreads();
  const int ticket = sticket;
  if (ticket < ATTN_BLKS - WORK_BLKS) return;

  // wait until ALL attn contributions are in
  if (t == 0) {
    while (aloadi(c1) < ATTN_BLKS) __builtin_amdgcn_s_sleep(2);
  }
  __syncthreads();

  if (ticket < ATTN_BLKS - TAIL_BLKS) {
    // ---------------- phase 2: gate GEMM (48 blocks) ----------------
    const int rid = ticket - (ATTN_BLKS - WORK_BLKS);   // 0..47
    const int jg = rid % 12, ks = rid / 12;
    const int j0 = jg * 64;
    const int jl = (t & 31) * 2;
    const int b0 = (t >> 5) * 4;
    float* wlds = smem;           // [64][64]
    float* clds = smem + 4096;    // [32][64]

    float acc[2][4] = {};
#pragma unroll
    for (int kt = 0; kt < 2; ++kt) {
      const int k0 = ks * 128 + kt * 64;
      __syncthreads();
#pragma unroll
      for (int q = 0; q < 4; ++q) {
        int idx = q * 256 + t; int r = idx >> 4, f4 = (idx & 15) * 4;
        *(float4*)&wlds[r * 64 + f4] = *(const float4*)&WtA[(size_t)(k0 + r) * G3_ + j0 + f4];
      }
#pragma unroll
      for (int q = 0; q < 8; ++q) {
        int idx = q * 256 + t; int bb = idx >> 6, k = idx & 63;
        clds[bb * 64 + k] = aload(&ctx_raw[bb * C_ + k0 + k]);
      }
      __syncthreads();
#pragma unroll 8
      for (int k = 0; k < 64; ++k) {
        float w0 = wlds[k * 64 + jl], w1 = wlds[k * 64 + jl + 1];
        float x0 = clds[b0 * 64 + k], x1 = clds[(b0 + 1) * 64 + k];
        float x2 = clds[(b0 + 2) * 64 + k], x3 = clds[(b0 + 3) * 64 + k];
        acc[0][0] += w0 * x0; acc[0][1] += w0 * x1; acc[0][2] += w0 * x2; acc[0][3] += w0 * x3;
        acc[1][0] += w1 * x0; acc[1][1] += w1 * x1; acc[1][2] += w1 * x2; acc[1][3] += w1 * x3;
      }
    }
#pragma unroll
    for (int i = 0; i < 2; ++i)
#pragma unroll
      for (int q = 0; q < 4; ++q)
        unsafeAtomicAdd(&gi_raw[(size_t)(b0 + q) * G3_ + j0 + jl + i], acc[i][q]);

    float acb[2][4] = {};
    {
      const int k0 = ks * 64;
      __syncthreads();
#pragma unroll
      for (int q = 0; q < 4; ++q) {
        int idx = q * 256 + t; int r = idx >> 4, f4 = (idx & 15) * 4;
        *(float4*)&wlds[r * 64 + f4] = *(const float4*)&WtH[(size_t)(k0 + r) * G3_ + j0 + f4];
      }
#pragma unroll
      for (int q = 0; q < 8; ++q) {
        int idx = q * 256 + t; int bb = idx >> 6, k = idx & 63;
        clds[bb * 64 + k] = h[bb * H_ + k0 + k];   // h from prev step: plain OK
      }
      __syncthreads();
#pragma unroll 8
      for (int k = 0; k < 64; ++k) {
        float w0 = wlds[k * 64 + jl], w1 = wlds[k * 64 + jl + 1];
        float x0 = clds[b0 * 64 + k], x1 = clds[(b0 + 1) * 64 + k];
        float x2 = clds[(b0 + 2) * 64 + k], x3 = clds[(b0 + 3) * 64 + k];
        acb[0][0] += w0 * x0; acb[0][1] += w0 * x1; acb[0][2] += w0 * x2; acb[0][3] += w0 * x3;
        acb[1][0] += w1 * x0; acb[1][1] += w1 * x1; acb[1][2] += w1 * x2; acb[1][3] += w1 * x3;
      }
    }
#pragma unroll
    for (int i = 0; i < 2; ++i)
#pragma unroll
      for (int q = 0; q < 4; ++q)
        unsafeAtomicAdd(&gh_raw[(size_t)(b0 + q) * G3_ + j0 + jl + i], acb[i][q]);

    asm volatile("s_waitcnt vmcnt(0)" ::: "memory");
    __syncthreads();
    if (t == 0) atomicAdd(c2, 1);
    return;
  }

  // ---------------- phase 3: tail (32 blocks, one per b) ----------------
  if (t == 0) {
    while (aloadi(c2) < GATE_BLKS) __builtin_amdgcn_s_sleep(2);
  }
  __syncthreads();
  {
    const int b = ticket - (ATTN_BLKS - TAIL_BLKS);
    float* shn = smem;            // [256]
    float* ss1 = smem + 256;      // [256]
    float* sst = smem + 512;      // [64]
    const int prev = pre[b];
    const float invl = 1.0f / aload(&l_total[b]);
    // j = t, t+256, t+512 (r,z,n rows for h-index t)
    float gi0 = aload(&gi_raw[b * G3_ + t]);
    float gi1 = aload(&gi_raw[b * G3_ + t + 256]);
    float gi2 = aload(&gi_raw[b * G3_ + t + 512]);
    float gh0 = aload(&gh_raw[b * G3_ + t]);
    float gh1 = aload(&gh_raw[b * G3_ + t + 256]);
    float gh2 = aload(&gh_raw[b * G3_ + t + 512]);
    const float h_old = h[b * H_ + t];
    __syncthreads();   // all loads done before any reset
    // resets for next step
    gi_raw[b * G3_ + t] = 0.0f; gi_raw[b * G3_ + t + 256] = 0.0f; gi_raw[b * G3_ + t + 512] = 0.0f;
    gh_raw[b * G3_ + t] = 0.0f; gh_raw[b * G3_ + t + 256] = 0.0f; gh_raw[b * G3_ + t + 512] = 0.0f;
    ctx_raw[b * C_ + t] = 0.0f; ctx_raw[b * C_ + t + 256] = 0.0f;
    if (t == 0) l_total[b] = 0.0f;

    const float* wo = WtO + (size_t)prev * G3_;
    gi0 = gi0 * invl + b_gru_ih[t]       + wo[t];
    gi1 = gi1 * invl + b_gru_ih[t + 256] + wo[t + 256];
    gi2 = gi2 * invl + b_gru_ih[t + 512] + wo[t + 512];
    gh0 += b_gru_hh[t]; gh1 += b_gru_hh[t + 256]; gh2 += b_gru_hh[t + 512];
    const float r = fast_sigmoid(gi0 + gh0);
    const float z = fast_sigmoid(gi1 + gh1);
    const float nn = fast_tanh(gi2 + r * gh2);
    const float hnew = (1.0f - z) * nn + z * h_old;
    h[b * H_ + t] = hnew;
    shn[t] = hnew;
    __syncthreads();

    // s1 and pp for this thread's output index t (coalesced transposed weights)
    {
      float a1 = b_s1[t], a2 = b_h2h[t];
      const float* w1 = Wt_s1 + t;
      const float* w2 = Wt_h2h + t;
#pragma unroll 8
      for (int c = 0; c < H_; ++c) {
        float v = shn[c];
        a1 += w1[(size_t)c * H_] * v;
        a2 += w2[(size_t)c * H_] * v;
      }
      ss1[t] = a1;
      pp[b * H_ + t] = a2;
    }
    __syncthreads();

    for (int v = wv; v < V_; v += 4) {
      float4 wr = *(const float4*)&w_s2[(size_t)v * H_ + lane * 4];
      float4 sv = *(const float4*)&ss1[lane * 4];
      float acc = wr.x * sv.x + wr.y * sv.y + wr.z * sv.z + wr.w * sv.w;
#pragma unroll
      for (int off = 32; off > 0; off >>= 1) acc += __shfl_xor(acc, off);
      if (lane == 0) sst[v] = acc + b_s2[v];
    }
    __syncthreads();

    if (t < 64) {
      float val = (lane < V_) ? sst[lane] : -INFINITY;
      float m = val;
#pragma unroll
      for (int off = 32; off > 0; off >>= 1) m = fmaxf(m, __shfl_xor(m, off));
      unsigned long long msk = __ballot(val == m);
      int amax = __ffsll(msk) - 1;   // first index achieving max (matches jnp.argmax)
      float e = (lane < V_) ? __expf(val - m) : 0.0f;
      float ssum = e;
#pragma unroll
      for (int off = 32; off > 0; off >>= 1) ssum += __shfl_xor(ssum, off);
      if (lane < V_) out[((size_t)b * T_ + tstep) * V_ + lane] = e / ssum;
      if (lane == 0) pre[b] = amax;
    }
  }
}

extern "C" void kernel_launch(void* const* d_in, const int* in_sizes, int n_in,
                              void* d_out, int out_size, void* d_ws, size_t ws_size,
                              hipStream_t stream) {
  (void)in_sizes; (void)n_in; (void)out_size; (void)ws_size;
  const float* feat     = (const float*)d_in[0];
  const float* w_i2h    = (const float*)d_in[1];
  const float* w_h2h    = (const float*)d_in[2];
  const float* b_h2h    = (const float*)d_in[3];
  const float* w_score  = (const float*)d_in[4];
  const float* w_gru_ih = (const float*)d_in[5];
  const float* w_gru_hh = (const float*)d_in[6];
  const float* b_gru_ih = (const float*)d_in[7];
  const float* b_gru_hh = (const float*)d_in[8];
  const float* w_s1     = (const float*)d_in[9];
  const float* b_s1     = (const float*)d_in[10];
  const float* w_s2     = (const float*)d_in[11];
  const float* b_s2     = (const float*)d_in[12];
  float* out = (float*)d_out;

  char* ws = (char*)d_ws;
  size_t off = 0;
  auto alloc = [&](size_t bytes) { void* p = ws + off; off += (bytes + 255) & ~(size_t)255; return p; };
  _Float16* fph   = (_Float16*)alloc((size_t)B_ * N_ * H_ * 2);   // 16.8 MB
  _Float16* feath = (_Float16*)alloc((size_t)B_ * N_ * C_ * 2);   // 33.6 MB
  float* ctx_raw  = (float*)alloc((size_t)B_ * C_ * 4);
  float* l_total  = (float*)alloc((size_t)B_ * 4);
  float* gi_raw   = (float*)alloc((size_t)B_ * G3_ * 4);
  float* gh_raw   = (float*)alloc((size_t)B_ * G3_ * 4);
  float* WtA      = (float*)alloc((size_t)C_ * G3_ * 4);          // [c][j]
  float* WtO      = (float*)alloc((size_t)V_ * G3_ * 4);          // [v][j]
  float* WtH      = (float*)alloc((size_t)H_ * G3_ * 4);          // [c][j]
  float* Wt_s1    = (float*)alloc((size_t)H_ * H_ * 4);
  float* Wt_h2h   = (float*)alloc((size_t)H_ * H_ * 4);
  float* h        = (float*)alloc((size_t)B_ * H_ * 4);
  float* pp       = (float*)alloc((size_t)B_ * H_ * 4);
  int*   pre      = (int*)alloc((size_t)B_ * 4);
  int*   cnt      = (int*)alloc((size_t)T_ * 2 * 4);

  init_kernel<<<128, 256, 0, stream>>>(b_h2h, h, pp, pre, ctx_raw, l_total, gi_raw, gh_raw, cnt);
  fp_gemm<<<dim3((B_ * N_) / 64, H_ / 64), 256, 0, stream>>>(feat, w_i2h, fph);
  feat_to_fp16<<<(B_ * N_ * C_ / 4 + 255) / 256, 256, 0, stream>>>(feat, feath, B_ * N_ * C_ / 4);
  transpose_split<<<(G3_ * CV_ + 255) / 256, 256, 0, stream>>>(w_gru_ih, WtA, WtO, G3_, CV_, C_);
  transpose_split<<<(G3_ * H_ + 255) / 256, 256, 0, stream>>>(w_gru_hh, WtH, WtH, G3_, H_, H_);
  transpose_split<<<(H_ * H_ + 255) / 256, 256, 0, stream>>>(w_s1, Wt_s1, Wt_s1, H_, H_, H_);
  transpose_split<<<(H_ * H_ + 255) / 256, 256, 0, stream>>>(w_h2h, Wt_h2h, Wt_h2h, H_, H_, H_);

  for (int tstep = 0; tstep < T_; ++tstep) {
    step_fused<<<ATTN_BLKS, 256, 0, stream>>>(
        tstep, feath, fph, w_score, pp, ctx_raw, l_total, gi_raw, gh_raw,
        WtA, WtH, WtO, b_gru_ih, b_gru_hh, Wt_s1, b_s1, Wt_h2h, b_h2h,
        w_s2, b_s2, h, pre, cnt, out);
  }
}